// Round 8
// baseline (258.447 us; speedup 1.0000x reference)
//
#include <hip/hip_runtime.h>
#include <hip/hip_bf16.h>
#include <stdint.h>

// Problem constants
#define Bn  4
#define Nn  10000
#define KRn 5
#define KAn 8
#define Cn  32
#define On  64
#define Kk  2
#define RN  8                  // rotations = KA
#define MT  16                 // points per block (10000 = 625*16, exact)
#define LDX 264                // LDS row stride (bf16 elems): 256 + 8 pad

typedef __attribute__((ext_vector_type(8))) short bf16x8;
typedef __attribute__((ext_vector_type(4))) float f32x4;
typedef __attribute__((ext_vector_type(2))) float f32x2;
typedef __attribute__((ext_vector_type(4))) unsigned short u16x4;
typedef __attribute__((ext_vector_type(4))) unsigned int u32x4;

static __device__ __forceinline__ unsigned int bfpack2(float a, float b) {
  unsigned int ua = __builtin_bit_cast(unsigned int, a);
  unsigned int ub = __builtin_bit_cast(unsigned int, b);
  ua = (ua + 0x7FFFu + ((ua >> 16) & 1u)) >> 16;
  ub = (ub + 0x7FFFu + ((ub >> 16) & 1u)) >> 16;
  return ua | (ub << 16);
}
static __device__ __forceinline__ unsigned short bf1(float a) {
  unsigned int ua = __builtin_bit_cast(unsigned int, a);
  return (unsigned short)((ua + 0x7FFFu + ((ua >> 16) & 1u)) >> 16);
}
static __device__ __forceinline__ float bfup(unsigned short u) {
  return __builtin_bit_cast(float, (unsigned int)u << 16);
}

// prep: (a) signal -> bf16 (L2-resident gather working set: 2.56 MB total)
//       (b) un-rotated summed kernel wk, B/A-fragment-ready
//       (c) bconst[o] = K * sum_pq bias
__global__ void prep_kernel(const float* __restrict__ signal,
                            const float* __restrict__ kernels,
                            const float* __restrict__ bias,
                            unsigned short* __restrict__ wk,
                            float* __restrict__ bconst,
                            unsigned short* __restrict__ sigbf) {
  int tid = blockIdx.x * 256 + threadIdx.x;
  if (tid < (Bn * Nn * Cn) / 8) {
    const f32x4* s = (const f32x4*)(signal + (size_t)tid * 8);
    f32x4 v0 = s[0], v1 = s[1];
    u32x4 o;
    o.x = bfpack2(v0.x, v0.y); o.y = bfpack2(v0.z, v0.w);
    o.z = bfpack2(v1.x, v1.y); o.w = bfpack2(v1.z, v1.w);
    *(u32x4*)(sigbf + (size_t)tid * 8) = o;
  }
  if (tid < KRn * KAn * 4 * 64) {
    int lane = tid & 63;
    int ot   = (tid >> 6) & 3;
    int q    = (tid >> 8) & 7;
    int p    = tid >> 11;
    int o  = ot * 16 + (lane & 15);
    int cb = (lane >> 4) * 8;
    const float* k0 = kernels + (((p * KAn + q) * On + o) * Cn + cb);
    const float* k1 = k0 + KRn * KAn * On * Cn;  // g=1
    unsigned short v[8];
#pragma unroll
    for (int j = 0; j < 8; ++j) v[j] = bf1(k0[j] + k1[j]);
    reinterpret_cast<bf16x8*>(wk)[tid] = *reinterpret_cast<const bf16x8*>(v);
  }
  if (blockIdx.x == 0 && threadIdx.x < On) {
    float s = 0.f;
    for (int pq = 0; pq < KRn * KAn; ++pq) s += bias[pq * On + (int)threadIdx.x];
    bconst[threadIdx.x] = (float)Kk * s;
  }
}

// Fused kernel: bf16 gather+interp -> LDS; swapped-operand MFMA so the output
// is o-in-register / n-in-lane -> full-line dwordx4 epilogue stores.
__global__ __launch_bounds__(256, 6) void conv_kernel(
    const unsigned short* __restrict__ sigbf,
    const float* __restrict__ bary,
    const unsigned short* __restrict__ wk,
    const float* __restrict__ bconst,
    float* __restrict__ out) {
  __shared__ __align__(16) unsigned short xs[MT * LDX];  // 8.25 KB

  const int b    = blockIdx.y;
  const int m0   = blockIdx.x * MT;
  const int tid  = threadIdx.x;
  const int lane = tid & 63;
  const int wv   = tid >> 6;           // wave 0..3
  const int lm   = lane & 15;
  const int lg   = lane >> 4;
  const int sq   = lane >> 3;          // q of this 8-lane group
  const int cv   = lane & 7;           // channel-vec (4 ch) within row

  const unsigned short* sigb = sigbf + (size_t)b * Nn * Cn;
  const float* baryb = bary + (size_t)b * Nn * 240;
  const bf16x8* wkf  = reinterpret_cast<const bf16x8*>(wk);

  f32x4 acc[2][4];                     // [rr][ot] -> 32 acc regs
#pragma unroll
  for (int rr = 0; rr < 2; ++rr)
#pragma unroll
    for (int ot = 0; ot < 4; ++ot) acc[rr][ot] = (f32x4){0.f, 0.f, 0.f, 0.f};

  for (int p = 0; p < KRn; ++p) {
    __syncthreads();                   // previous chunk's reads done
    // ---- stage chunk p: bf16 gather + interp -> xs ----
#pragma unroll
    for (int k = 0; k < 4; ++k) {
      int pt = k * 4 + wv;
      const float* bb = baryb + (size_t)(m0 + pt) * 240 + p * 48 + sq * 6;
      f32x2 p0 = *(const f32x2*)(bb);
      f32x2 p1 = *(const f32x2*)(bb + 2);
      f32x2 p2 = *(const f32x2*)(bb + 4);
      u16x4 a0 = *(const u16x4*)(sigb + (size_t)(int)p0.x * Cn + cv * 4);
      u16x4 a1 = *(const u16x4*)(sigb + (size_t)(int)p1.x * Cn + cv * 4);
      u16x4 a2 = *(const u16x4*)(sigb + (size_t)(int)p2.x * Cn + cv * 4);
      f32x4 s0 = {bfup(a0.x), bfup(a0.y), bfup(a0.z), bfup(a0.w)};
      f32x4 s1 = {bfup(a1.x), bfup(a1.y), bfup(a1.z), bfup(a1.w)};
      f32x4 s2 = {bfup(a2.x), bfup(a2.y), bfup(a2.z), bfup(a2.w)};
      f32x4 v = p0.y * s0 + p1.y * s1 + p2.y * s2;
      unsigned long long pk = (unsigned long long)bfpack2(v.x, v.y) |
                              ((unsigned long long)bfpack2(v.z, v.w) << 32);
      *(unsigned long long*)(&xs[pt * LDX + sq * 32 + cv * 4]) = pk;
    }
    __syncthreads();                   // xs fully staged
    // ---- GEMM chunk p: swapped operands (W^T as A, x^T as B) ----
#pragma unroll
    for (int qp = 0; qp < 8; ++qp) {
      const bf16x8* wp = wkf + (size_t)(p * 8 + qp) * 256 + lane;
      bf16x8 Bf0 = wp[0], Bf1 = wp[64], Bf2 = wp[128], Bf3 = wp[192];
#pragma unroll
      for (int rr = 0; rr < 2; ++rr) {
        int q = (qp - (wv * 2 + rr)) & 7;  // rotation: chunk q -> output ring r
        bf16x8 a = *(const bf16x8*)(&xs[lm * LDX + q * 32 + lg * 8]);
        acc[rr][0] = __builtin_amdgcn_mfma_f32_16x16x32_bf16(Bf0, a, acc[rr][0], 0, 0, 0);
        acc[rr][1] = __builtin_amdgcn_mfma_f32_16x16x32_bf16(Bf1, a, acc[rr][1], 0, 0, 0);
        acc[rr][2] = __builtin_amdgcn_mfma_f32_16x16x32_bf16(Bf2, a, acc[rr][2], 0, 0, 0);
        acc[rr][3] = __builtin_amdgcn_mfma_f32_16x16x32_bf16(Bf3, a, acc[rr][3], 0, 0, 0);
      }
    }
  }

  // ---- epilogue: D layout is o=(ot*16+lg*4+i), n=(m0+lm) -> dwordx4 stores ----
#pragma unroll
  for (int rr = 0; rr < 2; ++rr) {
    int r = wv * 2 + rr;
    float* rowp = out + (((size_t)b * RN + r) * Nn + m0 + lm) * On;
#pragma unroll
    for (int ot = 0; ot < 4; ++ot) {
      f32x4 bc4 = *(const f32x4*)(bconst + ot * 16 + lg * 4);
      f32x4 v = acc[rr][ot] + bc4;
      *(f32x4*)(rowp + ot * 16 + lg * 4) = v;
    }
  }
}

extern "C" void kernel_launch(void* const* d_in, const int* in_sizes, int n_in,
                              void* d_out, int out_size, void* d_ws, size_t ws_size,
                              hipStream_t stream) {
  const float* signal  = (const float*)d_in[0];
  const float* bary    = (const float*)d_in[1];
  const float* kernels = (const float*)d_in[2];
  const float* bias    = (const float*)d_in[3];
  float* out = (float*)d_out;

  // ws layout: wk (160 KB) | bconst (256 B) | sigbf (2.56 MB)
  unsigned short* wk = (unsigned short*)d_ws;
  float* bconst = (float*)((char*)d_ws + 163840);
  unsigned short* sigbf = (unsigned short*)((char*)d_ws + 164096);

  hipLaunchKernelGGL(prep_kernel, dim3(625), dim3(256), 0, stream,
                     signal, kernels, bias, wk, bconst, sigbf);
  dim3 grid(Nn / MT, Bn);
  hipLaunchKernelGGL(conv_kernel, grid, dim3(256), 0, stream,
                     sigbf, bary, wk, bconst, out);
}

// Round 10
// 209.885 us; speedup vs baseline: 1.2314x; 1.2314x over previous
//
#include <hip/hip_runtime.h>
#include <hip/hip_bf16.h>
#include <stdint.h>

// Problem constants
#define Bn  4
#define Nn  10000
#define KRn 5
#define KAn 8
#define Cn  32
#define On  64
#define Kk  2
#define RN  8                  // rotations = KA
#define MT  32                 // points per block
#define NT  313                // tiles per batch = ceil(10000/32)
#define LDX 264                // LDS row stride (bf16 elems): 256 + 8 pad

typedef __attribute__((ext_vector_type(8))) short bf16x8;
typedef __attribute__((ext_vector_type(4))) float f32x4;
typedef __attribute__((ext_vector_type(2))) float f32x2;
typedef __attribute__((ext_vector_type(4))) unsigned short u16x4;
typedef __attribute__((ext_vector_type(4))) unsigned int u32x4;

static __device__ __forceinline__ unsigned int bfpack2(float a, float b) {
  unsigned int ua = __builtin_bit_cast(unsigned int, a);
  unsigned int ub = __builtin_bit_cast(unsigned int, b);
  ua = (ua + 0x7FFFu + ((ua >> 16) & 1u)) >> 16;
  ub = (ub + 0x7FFFu + ((ub >> 16) & 1u)) >> 16;
  return ua | (ub << 16);
}
static __device__ __forceinline__ unsigned short bf1(float a) {
  unsigned int ua = __builtin_bit_cast(unsigned int, a);
  return (unsigned short)((ua + 0x7FFFu + ((ua >> 16) & 1u)) >> 16);
}
static __device__ __forceinline__ float bfup(unsigned short u) {
  return __builtin_bit_cast(float, (unsigned int)u << 16);
}

// prep: (a) signal -> bf16 (gather hot-set 640 KB/batch), (b) summed un-rotated
// kernel wk in fragment layout, (c) bconst[o] = K * sum_pq bias.
__global__ void prep_kernel(const float* __restrict__ signal,
                            const float* __restrict__ kernels,
                            const float* __restrict__ bias,
                            unsigned short* __restrict__ wk,
                            float* __restrict__ bconst,
                            unsigned short* __restrict__ sigbf) {
  int tid = blockIdx.x * 256 + threadIdx.x;
  if (tid < (Bn * Nn * Cn) / 8) {
    const f32x4* s = (const f32x4*)(signal + (size_t)tid * 8);
    f32x4 v0 = s[0], v1 = s[1];
    u32x4 o;
    o.x = bfpack2(v0.x, v0.y); o.y = bfpack2(v0.z, v0.w);
    o.z = bfpack2(v1.x, v1.y); o.w = bfpack2(v1.z, v1.w);
    *(u32x4*)(sigbf + (size_t)tid * 8) = o;
  }
  if (tid < KRn * KAn * 4 * 64) {
    int lane = tid & 63;
    int ot   = (tid >> 6) & 3;
    int q    = (tid >> 8) & 7;
    int p    = tid >> 11;
    int o  = ot * 16 + (lane & 15);
    int cb = (lane >> 4) * 8;
    const float* k0 = kernels + (((p * KAn + q) * On + o) * Cn + cb);
    const float* k1 = k0 + KRn * KAn * On * Cn;  // g=1
    unsigned short v[8];
#pragma unroll
    for (int j = 0; j < 8; ++j) v[j] = bf1(k0[j] + k1[j]);
    reinterpret_cast<bf16x8*>(wk)[tid] = *reinterpret_cast<const bf16x8*>(v);
  }
  if (blockIdx.x == 0 && threadIdx.x < On) {
    float s = 0.f;
    for (int pq = 0; pq < KRn * KAn; ++pq) s += bias[pq * On + (int)threadIdx.x];
    bconst[threadIdx.x] = (float)Kk * s;
  }
}

// MT=32, batch-pinned XCD swizzle, bary one chunk ahead (regs->bs LDS),
// bf16 gather+interp -> xs, swapped-operand MFMA, dwordx4 epilogue.
__global__ __launch_bounds__(256, 4) void conv_kernel(
    const unsigned short* __restrict__ sigbf,
    const float* __restrict__ bary,
    const unsigned short* __restrict__ wk,
    const float* __restrict__ bconst,
    float* __restrict__ out) {
  __shared__ __align__(16) unsigned short xs[MT * LDX];  // 16.9 KB
  __shared__ __align__(16) float bs[MT * 48];            // 6 KB

  // batch-pinned XCD swizzle: XCD = g%8 (round-robin heuristic); b = (g%8)/2
  // so each XCD only gathers ONE batch's 640 KB signal (L2-resident).
  const int g = blockIdx.x;
  const int b = (g & 7) >> 1;
  const int t = ((g >> 3) << 1) | (g & 1);
  if (t >= NT) return;
  const int m0 = t * MT;

  const int tid  = threadIdx.x;
  const int lane = tid & 63;
  const int wv   = tid >> 6;           // wave 0..3
  const int lm   = lane & 15;
  const int lg   = lane >> 4;
  const int sq   = lane >> 3;          // q of this 8-lane group
  const int cv   = lane & 7;           // channel-vec (4 ch) within row

  const unsigned short* sigb = sigbf + (size_t)b * Nn * Cn;
  const bf16x8* wkf = reinterpret_cast<const bf16x8*>(wk);

  // bary identity: thread (bpt, bc8) owns 6 floats of point bn, ring-slot bc8
  const int bpt = tid >> 3;            // 0..31
  const int bc8 = tid & 7;             // 0..7
  const int bn  = m0 + bpt;
  const bool bvalid = bn < Nn;
  const float* bybase = bary + (size_t)(b * Nn + bn) * 240 + bc8 * 6;

  f32x2 br0, br1, br2;

#define BR(PP) do {                                                            \
    if (bvalid) {                                                              \
      const float* s_ = bybase + (PP) * 48;                                    \
      br0 = *(const f32x2*)(s_);                                               \
      br1 = *(const f32x2*)(s_ + 2);                                           \
      br2 = *(const f32x2*)(s_ + 4);                                           \
    } else { br0 = (f32x2){0.f, 0.f}; br1 = br0; br2 = br0; }                  \
  } while (0)

#define BW() do {                                                              \
    float* d_ = &bs[bpt * 48 + bc8 * 6];                                       \
    *(f32x2*)(d_) = br0; *(f32x2*)(d_ + 2) = br1; *(f32x2*)(d_ + 4) = br2;     \
  } while (0)

  // stage current bs chunk -> xs (bf16 gather + interp); zero rows give zeros
#define INTERP() do {                                                          \
    _Pragma("unroll")                                                          \
    for (int k = 0; k < 8; ++k) {                                              \
      int pt = k * 4 + wv;                                                     \
      const float* bb = &bs[pt * 48 + sq * 6];                                 \
      f32x2 p0 = *(const f32x2*)(bb);                                          \
      f32x2 p1 = *(const f32x2*)(bb + 2);                                      \
      f32x2 p2 = *(const f32x2*)(bb + 4);                                      \
      u16x4 a0 = *(const u16x4*)(sigb + (size_t)(int)p0.x * Cn + cv * 4);      \
      u16x4 a1 = *(const u16x4*)(sigb + (size_t)(int)p1.x * Cn + cv * 4);      \
      u16x4 a2 = *(const u16x4*)(sigb + (size_t)(int)p2.x * Cn + cv * 4);      \
      f32x4 s0 = {bfup(a0.x), bfup(a0.y), bfup(a0.z), bfup(a0.w)};             \
      f32x4 s1 = {bfup(a1.x), bfup(a1.y), bfup(a1.z), bfup(a1.w)};             \
      f32x4 s2 = {bfup(a2.x), bfup(a2.y), bfup(a2.z), bfup(a2.w)};             \
      f32x4 v = p0.y * s0 + p1.y * s1 + p2.y * s2;                             \
      unsigned long long pk = (unsigned long long)bfpack2(v.x, v.y) |          \
                              ((unsigned long long)bfpack2(v.z, v.w) << 32);   \
      *(unsigned long long*)(&xs[pt * LDX + sq * 32 + cv * 4]) = pk;           \
    }                                                                          \
  } while (0)

  f32x4 acc[2][2][4];                  // [rr][mt][ot] -> 64 acc regs
#pragma unroll
  for (int rr = 0; rr < 2; ++rr)
#pragma unroll
    for (int mt = 0; mt < 2; ++mt)
#pragma unroll
      for (int ot = 0; ot < 4; ++ot) acc[rr][mt][ot] = (f32x4){0.f, 0.f, 0.f, 0.f};

  // prologue: bary chunk 0 -> bs; stage chunk 0 -> xs
  BR(0); BW();
  __syncthreads();
  INTERP();

  for (int p = 0; p < KRn; ++p) {
    __syncthreads();                   // xs staged; bs free
    if (p < KRn - 1) BR(p + 1);        // HBM latency hides under GEMM

    // ---- GEMM chunk p: swapped operands, rotation-by-index ----
#pragma unroll
    for (int qp = 0; qp < 8; ++qp) {
      const bf16x8* wp = wkf + (size_t)(p * 8 + qp) * 256 + lane;
      bf16x8 Bf0 = wp[0], Bf1 = wp[64], Bf2 = wp[128], Bf3 = wp[192];
#pragma unroll
      for (int rr = 0; rr < 2; ++rr) {
        int q = (qp - (wv * 2 + rr)) & 7;  // chunk q feeds output ring r
#pragma unroll
        for (int mt = 0; mt < 2; ++mt) {
          bf16x8 a = *(const bf16x8*)(&xs[(mt * 16 + lm) * LDX + q * 32 + lg * 8]);
          acc[rr][mt][0] = __builtin_amdgcn_mfma_f32_16x16x32_bf16(Bf0, a, acc[rr][mt][0], 0, 0, 0);
          acc[rr][mt][1] = __builtin_amdgcn_mfma_f32_16x16x32_bf16(Bf1, a, acc[rr][mt][1], 0, 0, 0);
          acc[rr][mt][2] = __builtin_amdgcn_mfma_f32_16x16x32_bf16(Bf2, a, acc[rr][mt][2], 0, 0, 0);
          acc[rr][mt][3] = __builtin_amdgcn_mfma_f32_16x16x32_bf16(Bf3, a, acc[rr][mt][3], 0, 0, 0);
        }
      }
    }

    if (p < KRn - 1) {
      BW();
      __syncthreads();                 // bs chunk p+1 visible
      INTERP();                        // stage chunk p+1 -> xs
    }
  }

  // ---- epilogue: D is o-in-register / n-in-lane -> dwordx4 row stores ----
  f32x4 bc4[4];
#pragma unroll
  for (int ot = 0; ot < 4; ++ot) bc4[ot] = *(const f32x4*)(bconst + ot * 16 + lg * 4);
#pragma unroll
  for (int rr = 0; rr < 2; ++rr) {
    int r = wv * 2 + rr;
#pragma unroll
    for (int mt = 0; mt < 2; ++mt) {
      int n = m0 + mt * 16 + lm;
      if (n < Nn) {
        float* rowp = out + (((size_t)b * RN + r) * Nn + n) * On;
#pragma unroll
        for (int ot = 0; ot < 4; ++ot) {
          f32x4 v = acc[rr][mt][ot] + bc4[ot];
          *(f32x4*)(rowp + ot * 16 + lg * 4) = v;
        }
      }
    }
  }
#undef BR
#undef BW
#undef INTERP
}

extern "C" void kernel_launch(void* const* d_in, const int* in_sizes, int n_in,
                              void* d_out, int out_size, void* d_ws, size_t ws_size,
                              hipStream_t stream) {
  const float* signal  = (const float*)d_in[0];
  const float* bary    = (const float*)d_in[1];
  const float* kernels = (const float*)d_in[2];
  const float* bias    = (const float*)d_in[3];
  float* out = (float*)d_out;

  // ws layout: wk (160 KB) | bconst (256 B) | sigbf (2.56 MB)
  unsigned short* wk = (unsigned short*)d_ws;
  float* bconst = (float*)((char*)d_ws + 163840);
  unsigned short* sigbf = (unsigned short*)((char*)d_ws + 164096);

  hipLaunchKernelGGL(prep_kernel, dim3(625), dim3(256), 0, stream,
                     signal, kernels, bias, wk, bconst, sigbf);
  hipLaunchKernelGGL(conv_kernel, dim3(8 * 157), dim3(256), 0, stream,
                     sigbf, bary, wk, bconst, out);
}